// Round 10
// baseline (1186.024 us; speedup 1.0000x reference)
//
#include <hip/hip_runtime.h>

typedef __bf16 bf16_t;
typedef __bf16 bf16x4 __attribute__((ext_vector_type(4)));
typedef __bf16 bf16x8 __attribute__((ext_vector_type(8)));
typedef float f32x4 __attribute__((ext_vector_type(4)));

#define QKV_SEG 33554432L  // elements per q/k/v segment: 2048 win * 8 heads * 64 tok * 32 d
#define MFMA __builtin_amdgcn_mfma_f32_16x16x32_bf16

// ---------------- weight fp32 -> bf16 convert ----------------
__global__ __launch_bounds__(256) void cvt_kernel(const float* __restrict__ src,
                                                  bf16_t* __restrict__ dst) {
  int i = (blockIdx.x * 256 + threadIdx.x) * 4;
  float4 v = *(const float4*)(src + i);
  bf16x4 o;
  o[0] = (bf16_t)v.x; o[1] = (bf16_t)v.y; o[2] = (bf16_t)v.z; o[3] = (bf16_t)v.w;
  *(bf16x4*)(dst + i) = o;
}

// ---------------- LayerNorm (+ optional shift/window-partition gather) ----------------
__global__ __launch_bounds__(256) void ln_kernel(const float* __restrict__ src,
                                                 const float* __restrict__ gw,
                                                 const float* __restrict__ gb,
                                                 bf16_t* __restrict__ dst,
                                                 int shifted) {
  int lane = threadIdx.x & 63, wv = threadIdx.x >> 6;
  long m = (long)blockIdx.x * 4 + wv;  // dest row (window-token order if shifted)
  long srow;
  if (shifted) {
    long b_ = m >> 6; int tok = (int)(m & 63);
    int bb = (int)(b_ >> 8), win = (int)(b_ & 255);
    int wh = win >> 4, ww = win & 15;
    int ii = tok >> 3, jj = tok & 7;
    int hh = (wh * 8 + ii + 4) & 127, wp = (ww * 8 + jj + 4) & 127;
    srow = ((long)bb << 14) + (hh << 7) + wp;
  } else {
    srow = m;
  }
  float4 v = *(const float4*)(src + srow * 256 + lane * 4);
  float s = v.x + v.y + v.z + v.w;
  float s2 = v.x * v.x + v.y * v.y + v.z * v.z + v.w * v.w;
#pragma unroll
  for (int msk = 1; msk < 64; msk <<= 1) {
    s += __shfl_xor(s, msk);
    s2 += __shfl_xor(s2, msk);
  }
  float mean = s * (1.f / 256.f);
  float var = s2 * (1.f / 256.f) - mean * mean;
  float rs = rsqrtf(var + 1e-5f);
  float4 g4 = *(const float4*)(gw + lane * 4);
  float4 b4 = *(const float4*)(gb + lane * 4);
  bf16x4 o;
  o[0] = (bf16_t)((v.x - mean) * rs * g4.x + b4.x);
  o[1] = (bf16_t)((v.y - mean) * rs * g4.y + b4.y);
  o[2] = (bf16_t)((v.z - mean) * rs * g4.z + b4.z);
  o[3] = (bf16_t)((v.w - mean) * rs * g4.w + b4.w);
  *(bf16x4*)(dst + m * 256 + lane * 4) = o;
}

// ---------------- streaming GEMM: zero LDS, zero barriers ----------------
// Each wave independently computes a 64-tok x 64-n tile. A read directly from
// global (coalesced 16B/lane rows, streams HBM->L3 once; same-A blocks are
// dispatch-adjacent via n-fastest grid). B (weights <=512KB) is L2-resident.
// No inter-wave coupling: a load stall affects only its own wave; 12+ indep
// waves/CU provide the memory parallelism (LN-kernel regime, ~6 TB/s).
// Outer kc4 loop not unrolled (bounds VGPR); inner 4 chunks unrolled for ILP.
// EPI 0: qkv scatter  EPI 1: proj+reverse-shift+resid  EPI 2: gelu->bf16[M][1024]  EPI 3: +resid fp32
template <int EPI, int K>
__global__ __launch_bounds__(256) void gemm_stream(const bf16_t* __restrict__ A,
                                                   const bf16_t* __restrict__ Bw,
                                                   const float* __restrict__ bias,
                                                   bf16_t* __restrict__ out_bf, float* out_f,
                                                   const float* resid) {
  int lane = threadIdx.x & 63, wv = threadIdx.x >> 6;
  long m0 = (long)blockIdx.y * 256 + wv * 64;
  int n0 = blockIdx.x * 64;
  int lr = lane & 15, lk = (lane >> 4) * 8, g = lane >> 4;
  const bf16_t* Ab = A + m0 * K + lk;
  const bf16_t* Bb = Bw + (long)n0 * K + lk;

  f32x4 acc[4][4] = {};
  for (int kc4 = 0; kc4 < K / 128; ++kc4) {
#pragma unroll
    for (int ki = 0; ki < 4; ++ki) {
      int kc = kc4 * 4 + ki;
      bf16x8 af[4], bf_[4];
#pragma unroll
      for (int mf = 0; mf < 4; ++mf)
        af[mf] = *(const bf16x8*)(Ab + (long)(mf * 16 + lr) * K + kc * 32);
#pragma unroll
      for (int nf = 0; nf < 4; ++nf)
        bf_[nf] = *(const bf16x8*)(Bb + (long)(nf * 16 + lr) * K + kc * 32);
#pragma unroll
      for (int mf = 0; mf < 4; ++mf)
#pragma unroll
        for (int nf = 0; nf < 4; ++nf)
          acc[mf][nf] = MFMA(af[mf], bf_[nf], acc[mf][nf], 0, 0, 0);
    }
  }

#pragma unroll
  for (int mf = 0; mf < 4; ++mf) {
#pragma unroll
    for (int nf = 0; nf < 4; ++nf) {
      long mb = m0 + mf * 16 + 4 * g;  // 4-aligned row base (r=0..3 consecutive toks)
      int n = n0 + nf * 16 + lr;
      float bn = bias[n];
      if (EPI == 0) {
        long b_ = mb >> 6;
        int tok = (int)(mb & 63);  // 4-aligned, never crosses window boundary
        int which = n >> 8, rem = n & 255, head = rem >> 5, d = rem & 31;
        if (which == 2) {
          bf16x4 o;
#pragma unroll
          for (int r = 0; r < 4; ++r) o[r] = (bf16_t)(acc[mf][nf][r] + bn);
          *(bf16x4*)(out_bf + 2 * QKV_SEG + ((b_ * 8 + head) * 32 + d) * 64 + tok) = o;
        } else {
          long base = (long)which * QKV_SEG + ((b_ * 8 + head) * 64 + tok) * 32 + d;
#pragma unroll
          for (int r = 0; r < 4; ++r) out_bf[base + r * 32] = (bf16_t)(acc[mf][nf][r] + bn);
        }
      } else if (EPI == 1) {
#pragma unroll
        for (int r = 0; r < 4; ++r) {
          long m = mb + r;
          long b_ = m >> 6; int tok = (int)(m & 63);
          int bb = (int)(b_ >> 8), win = (int)(b_ & 255);
          int wh = win >> 4, ww = win & 15;
          int ii = tok >> 3, jj = tok & 7;
          int hh = (wh * 8 + ii + 4) & 127, wp = (ww * 8 + jj + 4) & 127;
          long dst = (((long)bb << 14) + (hh << 7) + wp) * 256 + n;
          out_f[dst] = acc[mf][nf][r] + bn + resid[dst];
        }
      } else if (EPI == 2) {
#pragma unroll
        for (int r = 0; r < 4; ++r) {
          float val = acc[mf][nf][r] + bn;
          float t = 0.5f * val * (1.0f + erff(val * 0.70710678118654752f));
          out_bf[(mb + r) * 1024 + n] = (bf16_t)t;
        }
      } else {
#pragma unroll
        for (int r = 0; r < 4; ++r) {
          long idx = (mb + r) * 256 + n;
          out_f[idx] = acc[mf][nf][r] + bn + resid[idx];
        }
      }
    }
  }
}

// ---------------- per-window attention: 4 waves x 2 heads ----------------
__global__ __launch_bounds__(256) void attn_kernel(const bf16_t* __restrict__ qkv,
                                                   const float* __restrict__ rpb,
                                                   bf16_t* __restrict__ attn_out) {
  __shared__ float rpb_s[1800];       // 225 x 8
  __shared__ bf16_t P[4][64][72];     // +8 pad: 144B stride -> 2-way (free)
  int tid = threadIdx.x, lane = tid & 63, wv = tid >> 6;
  long b_ = blockIdx.x;
  for (int i = tid; i < 1800; i += 256) rpb_s[i] = rpb[i];
  __syncthreads();
  const bf16_t* q = qkv;
  const bf16_t* k = qkv + QKV_SEG;
  const bf16_t* vt = qkv + 2 * QKV_SEG;
  int lr = lane & 15, lk = (lane >> 4) * 8, g = lane >> 4;
  const float scale = 0.17677669529663688f;  // 32^-0.5

  for (int hh = 0; hh < 2; ++hh) {
    int head = wv * 2 + hh;
    long base = (b_ * 8 + head) * 2048;
    bf16x8 af[4], bfr[4];
#pragma unroll
    for (int mf = 0; mf < 4; ++mf)
      af[mf] = *(const bf16x8*)(q + base + (mf * 16 + lr) * 32 + lk);
#pragma unroll
    for (int nf = 0; nf < 4; ++nf)
      bfr[nf] = *(const bf16x8*)(k + base + (nf * 16 + lr) * 32 + lk);
    f32x4 S[4][4] = {};
#pragma unroll
    for (int mf = 0; mf < 4; ++mf)
#pragma unroll
      for (int nf = 0; nf < 4; ++nf)
        S[mf][nf] = MFMA(af[mf], bfr[nf], S[mf][nf], 0, 0, 0);
#pragma unroll
    for (int mf = 0; mf < 4; ++mf)
#pragma unroll
      for (int nf = 0; nf < 4; ++nf)
#pragma unroll
        for (int r = 0; r < 4; ++r) {
          int i = mf * 16 + 4 * g + r, j = nf * 16 + lr;
          int rel = ((i >> 3) - (j >> 3) + 7) * 15 + ((i & 7) - (j & 7) + 7);
          S[mf][nf][r] = S[mf][nf][r] * scale + rpb_s[rel * 8 + head];
        }
#pragma unroll
    for (int mf = 0; mf < 4; ++mf) {
#pragma unroll
      for (int r = 0; r < 4; ++r) {
        float mx = fmaxf(fmaxf(S[mf][0][r], S[mf][1][r]), fmaxf(S[mf][2][r], S[mf][3][r]));
#pragma unroll
        for (int msk = 1; msk < 16; msk <<= 1) mx = fmaxf(mx, __shfl_xor(mx, msk));
        float sm = 0.f;
#pragma unroll
        for (int nf = 0; nf < 4; ++nf) {
          float e = __expf(S[mf][nf][r] - mx);
          S[mf][nf][r] = e;
          sm += e;
        }
#pragma unroll
        for (int msk = 1; msk < 16; msk <<= 1) sm += __shfl_xor(sm, msk);
        float is = 1.f / sm;
        int i = mf * 16 + 4 * g + r;
#pragma unroll
        for (int nf = 0; nf < 4; ++nf) P[wv][i][nf * 16 + lr] = (bf16_t)(S[mf][nf][r] * is);
      }
    }
    f32x4 O[4][2] = {};
#pragma unroll
    for (int ks = 0; ks < 2; ++ks) {
      int j0 = ks * 32;
      bf16x8 pa[4], vb[2];
#pragma unroll
      for (int mf = 0; mf < 4; ++mf) pa[mf] = *(const bf16x8*)(&P[wv][mf * 16 + lr][j0 + lk]);
#pragma unroll
      for (int nf = 0; nf < 2; ++nf)
        vb[nf] = *(const bf16x8*)(vt + base + (nf * 16 + lr) * 64 + j0 + lk);
#pragma unroll
      for (int mf = 0; mf < 4; ++mf)
#pragma unroll
        for (int nf = 0; nf < 2; ++nf)
          O[mf][nf] = MFMA(pa[mf], vb[nf], O[mf][nf], 0, 0, 0);
    }
#pragma unroll
    for (int mf = 0; mf < 4; ++mf)
#pragma unroll
      for (int nf = 0; nf < 2; ++nf)
#pragma unroll
        for (int r = 0; r < 4; ++r) {
          int i = mf * 16 + 4 * g + r, d = nf * 16 + lr;
          attn_out[(b_ * 64 + i) * 256 + head * 32 + d] = (bf16_t)O[mf][nf][r];
        }
  }
}

extern "C" void kernel_launch(void* const* d_in, const int* in_sizes, int n_in,
                              void* d_out, int out_size, void* d_ws, size_t ws_size,
                              hipStream_t stream) {
  const float* x = (const float*)d_in[0];
  const float* n1w = (const float*)d_in[1];
  const float* n1b = (const float*)d_in[2];
  const float* qkv_w = (const float*)d_in[3];
  const float* qkv_b = (const float*)d_in[4];
  const float* rpb = (const float*)d_in[5];
  const float* proj_w = (const float*)d_in[6];
  const float* proj_b = (const float*)d_in[7];
  const float* n2w = (const float*)d_in[8];
  const float* n2b = (const float*)d_in[9];
  const float* fc1_w = (const float*)d_in[10];
  const float* fc1_b = (const float*)d_in[11];
  const float* fc2_w = (const float*)d_in[12];
  const float* fc2_b = (const float*)d_in[13];
  float* out = (float*)d_out;

  char* ws = (char*)d_ws;
  bf16_t* bufA = (bf16_t*)ws;                       // qkv (201MB) then h (268MB)
  bf16_t* bufB = (bf16_t*)(ws + 268435456L);        // xw / attn_out / y (67MB)
  bf16_t* wq = (bf16_t*)(ws + 335544320L);          // bf16 weights (1.6MB)
  bf16_t* wp = wq + 196608;
  bf16_t* w1 = wp + 65536;
  bf16_t* w2 = w1 + 262144;

  // weights -> bf16
  cvt_kernel<<<192, 256, 0, stream>>>(qkv_w, wq);
  cvt_kernel<<<64, 256, 0, stream>>>(proj_w, wp);
  cvt_kernel<<<256, 256, 0, stream>>>(fc1_w, w1);
  cvt_kernel<<<256, 256, 0, stream>>>(fc2_w, w2);

  // LN1 + shift + window partition -> xw (bufB)
  ln_kernel<<<32768, 256, 0, stream>>>(x, n1w, n1b, bufB, 1);
  // QKV GEMM -> q/k/v_t (bufA)   M=131072 N=768 K=256
  gemm_stream<0, 256><<<dim3(12, 512), 256, 0, stream>>>(bufB, wq, qkv_b, bufA, nullptr, nullptr);
  // window attention -> attn_out (bufB)
  attn_kernel<<<2048, 256, 0, stream>>>(bufA, rpb, bufB);
  // proj + reverse shift + residual -> x1 (d_out, fp32)   N=256
  gemm_stream<1, 256><<<dim3(4, 512), 256, 0, stream>>>(bufB, wp, proj_b, nullptr, out, x);
  // LN2 -> y (bufB)
  ln_kernel<<<32768, 256, 0, stream>>>(out, n2w, n2b, bufB, 0);
  // FC1 + gelu -> h (bufA)   N=1024
  gemm_stream<2, 256><<<dim3(16, 512), 256, 0, stream>>>(bufB, w1, fc1_b, bufA, nullptr, nullptr);
  // FC2 + residual -> out (in-place x1 + y)   K=1024
  gemm_stream<3, 1024><<<dim3(4, 512), 256, 0, stream>>>(bufA, w2, fc2_b, nullptr, out, out);
}

// Round 11
// 794.074 us; speedup vs baseline: 1.4936x; 1.4936x over previous
//
#include <hip/hip_runtime.h>

typedef __bf16 bf16_t;
typedef __bf16 bf16x4 __attribute__((ext_vector_type(4)));
typedef __bf16 bf16x8 __attribute__((ext_vector_type(8)));
typedef float f32x4 __attribute__((ext_vector_type(4)));

#define QKV_SEG 33554432L  // elements per q/k/v segment: 2048 win * 8 heads * 64 tok * 32 d

#define GLDS(gp, lp)                                                                   \
  __builtin_amdgcn_global_load_lds((const __attribute__((address_space(1))) void*)(gp), \
                                   (__attribute__((address_space(3))) void*)(lp), 16, 0, 0)
#define BAR __builtin_amdgcn_s_barrier()
#define SCHED0 __builtin_amdgcn_sched_barrier(0)
#define MFMA __builtin_amdgcn_mfma_f32_16x16x32_bf16

// ---------------- weight fp32 -> bf16 convert ----------------
__global__ __launch_bounds__(256) void cvt_kernel(const float* __restrict__ src,
                                                  bf16_t* __restrict__ dst) {
  int i = (blockIdx.x * 256 + threadIdx.x) * 4;
  float4 v = *(const float4*)(src + i);
  bf16x4 o;
  o[0] = (bf16_t)v.x; o[1] = (bf16_t)v.y; o[2] = (bf16_t)v.z; o[3] = (bf16_t)v.w;
  *(bf16x4*)(dst + i) = o;
}

// ---------------- LayerNorm1 + shift + window-partition gather ----------------
__global__ __launch_bounds__(256) void ln_kernel(const float* __restrict__ src,
                                                 const float* __restrict__ gw,
                                                 const float* __restrict__ gb,
                                                 bf16_t* __restrict__ dst) {
  int lane = threadIdx.x & 63, wv = threadIdx.x >> 6;
  long m = (long)blockIdx.x * 4 + wv;  // dest row (window-token order)
  long b_ = m >> 6; int tok = (int)(m & 63);
  int bb = (int)(b_ >> 8), win = (int)(b_ & 255);
  int wh = win >> 4, ww = win & 15;
  int ii = tok >> 3, jj = tok & 7;
  int hh = (wh * 8 + ii + 4) & 127, wp = (ww * 8 + jj + 4) & 127;
  long srow = ((long)bb << 14) + (hh << 7) + wp;

  float4 v = *(const float4*)(src + srow * 256 + lane * 4);
  float s = v.x + v.y + v.z + v.w;
  float s2 = v.x * v.x + v.y * v.y + v.z * v.z + v.w * v.w;
#pragma unroll
  for (int msk = 1; msk < 64; msk <<= 1) {
    s += __shfl_xor(s, msk);
    s2 += __shfl_xor(s2, msk);
  }
  float mean = s * (1.f / 256.f);
  float var = s2 * (1.f / 256.f) - mean * mean;
  float rs = rsqrtf(var + 1e-5f);
  float4 g4 = *(const float4*)(gw + lane * 4);
  float4 b4 = *(const float4*)(gb + lane * 4);
  bf16x4 o;
  o[0] = (bf16_t)((v.x - mean) * rs * g4.x + b4.x);
  o[1] = (bf16_t)((v.y - mean) * rs * g4.y + b4.y);
  o[2] = (bf16_t)((v.z - mean) * rs * g4.z + b4.z);
  o[3] = (bf16_t)((v.w - mean) * rs * g4.w + b4.w);
  *(bf16x4*)(dst + m * 256 + lane * 4) = o;
}

// ---------------- GEMM (QKV / proj): BK=64 depth-2, counted vmcnt, XCD swizzle ----------------
// EPI 0: qkv scatter -> q/k/v_t bf16
// EPI 1: proj + reverse-shift + residual(x fp32) -> x1 bf16 (out_bf)
template <int EPI>
__global__ __launch_bounds__(256) void gemm_kernel(const bf16_t* __restrict__ A,
                                                   const bf16_t* __restrict__ Bw,
                                                   const float* __restrict__ bias, int K,
                                                   bf16_t* __restrict__ out_bf,
                                                   const float* resid) {
  __shared__ __align__(16) bf16_t As[2][8192];  // [buf][128*64]
  __shared__ __align__(16) bf16_t Bs[2][8192];
  int tid = threadIdx.x;
  int lane = tid & 63, wv = tid >> 6;
  int wm = wv >> 1, wn = wv & 1;

  int GX = gridDim.x, GY = gridDim.y;
  int flat = blockIdx.x + blockIdx.y * GX;
  int xcd = flat & 7, ii = flat >> 3;
  int iq = ii / GX;
  int by = xcd * (GY >> 3) + iq;
  int bx = ii - iq * GX;
  long m0 = (long)by * 128;
  int n0 = bx * 128;
  int lr = lane & 15, g = lane >> 4;

  int csw = (((lane & 7) ^ (lane >> 3)) << 3);
  const bf16_t* gA = A + (m0 + wv * 32 + (lane >> 3)) * K + csw;
  const bf16_t* gB = Bw + (long)(n0 + wv * 32 + (lane >> 3)) * K + csw;

  f32x4 acc[4][4] = {};

#define STAGE(buf, k0)                                                    \
  do {                                                                    \
    _Pragma("unroll") for (int s = 0; s < 4; ++s) {                       \
      GLDS(gA + (long)s * 8 * K + (k0), As[buf] + wv * 2048 + s * 512);   \
      GLDS(gB + (long)s * 8 * K + (k0), Bs[buf] + wv * 2048 + s * 512);   \
    }                                                                     \
  } while (0)

  int nt = K >> 6;
  STAGE(0, 0);
  for (int t = 0; t < nt; ++t) {
    int tb = t & 1;
    if (t + 1 < nt) {
      STAGE(tb ^ 1, (t + 1) << 6);
      asm volatile("s_waitcnt vmcnt(8)" ::: "memory");
    } else {
      asm volatile("s_waitcnt vmcnt(0)" ::: "memory");
    }
    BAR;
    SCHED0;
#pragma unroll
    for (int kk = 0; kk < 2; ++kk) {
      bf16x8 af[4], bfr[4];
#pragma unroll
      for (int mf = 0; mf < 4; ++mf)
        af[mf] = *(const bf16x8*)(As[tb] + (wm * 64 + mf * 16 + lr) * 64 +
                                  (((kk * 4 + g) ^ (lr & 7)) << 3));
#pragma unroll
      for (int nf = 0; nf < 4; ++nf)
        bfr[nf] = *(const bf16x8*)(Bs[tb] + (wn * 64 + nf * 16 + lr) * 64 +
                                   (((kk * 4 + g) ^ (lr & 7)) << 3));
#pragma unroll
      for (int mf = 0; mf < 4; ++mf)
#pragma unroll
        for (int nf = 0; nf < 4; ++nf)
          acc[mf][nf] = MFMA(af[mf], bfr[nf], acc[mf][nf], 0, 0, 0);
    }
    BAR;
  }
#undef STAGE

#pragma unroll
  for (int mf = 0; mf < 4; ++mf) {
#pragma unroll
    for (int nf = 0; nf < 4; ++nf) {
      long mb = m0 + wm * 64 + mf * 16 + 4 * g;
      int n = n0 + wn * 64 + nf * 16 + lr;
      float bn = bias[n];
      if (EPI == 0) {
        long b_ = mb >> 6;
        int tok = (int)(mb & 63);
        int which = n >> 8, rem = n & 255, head = rem >> 5, d = rem & 31;
        if (which == 2) {
          bf16x4 o;
#pragma unroll
          for (int r = 0; r < 4; ++r) o[r] = (bf16_t)(acc[mf][nf][r] + bn);
          *(bf16x4*)(out_bf + 2 * QKV_SEG + ((b_ * 8 + head) * 32 + d) * 64 + tok) = o;
        } else {
          long base = (long)which * QKV_SEG + ((b_ * 8 + head) * 64 + tok) * 32 + d;
#pragma unroll
          for (int r = 0; r < 4; ++r) out_bf[base + r * 32] = (bf16_t)(acc[mf][nf][r] + bn);
        }
      } else {
#pragma unroll
        for (int r = 0; r < 4; ++r) {
          long m = mb + r;
          long b_ = m >> 6; int tok = (int)(m & 63);
          int bb = (int)(b_ >> 8), win = (int)(b_ & 255);
          int wh = win >> 4, ww = win & 15;
          int jj0 = tok >> 3, jj = tok & 7;
          int hh = (wh * 8 + jj0 + 4) & 127, wp = (ww * 8 + jj + 4) & 127;
          long dst = (((long)bb << 14) + (hh << 7) + wp) * 256 + n;
          out_bf[dst] = (bf16_t)(acc[mf][nf][r] + bn + resid[dst]);
        }
      }
    }
  }
}

// ---------------- fused MLP v3: LN2 + FC1 + GeLU + FC2 + residual ----------------
// 32 tokens/block (grid 4096), 4 waves, 32KB LDS -> 4 blocks/CU.
// ys and hs XOR-swizzled (chunk ^= row&7, both write and read sides) -> no bank
// conflicts. hs double-buffered -> ONE barrier per hidden-chunk: FC2(hc) reads
// hs[p] while next FC1 writes hs[p^1]; iteration hc+1's barrier separates
// FC2(hc) from FC1(hc+2)'s overwrite of hs[p].
// x1 input is bf16 (x1b); final out = fp32 d_out written once here.
__global__ __launch_bounds__(256, 4) void mlp_kernel(const bf16_t* __restrict__ x1b,
                                                     float* __restrict__ out,
                                                     const float* __restrict__ gw,
                                                     const float* __restrict__ gb,
                                                     const bf16_t* __restrict__ w1,
                                                     const float* __restrict__ b1,
                                                     const bf16_t* __restrict__ w2,
                                                     const float* __restrict__ b2) {
  __shared__ __align__(16) bf16_t ys[32 * 256];      // 16 KB, swizzled
  __shared__ __align__(16) bf16_t hs[2][32 * 128];   // 2 x 8 KB, swizzled
  int tid = threadIdx.x, lane = tid & 63, wv = tid >> 6;
  long m0 = (long)blockIdx.x * 32;
  int lr = lane & 15, lk = (lane >> 4) * 8, g = lane >> 4;

  // ---- LN2 (bf16 in, bf16 swizzled LDS out): 8 rows per wave ----
  float4 g4 = *(const float4*)(gw + lane * 4);
  float4 b4 = *(const float4*)(gb + lane * 4);
#pragma unroll
  for (int i = 0; i < 8; ++i) {
    int r = wv * 8 + i;
    bf16x4 xv = *(const bf16x4*)(x1b + (m0 + r) * 256 + lane * 4);
    float v0 = (float)xv[0], v1 = (float)xv[1], v2 = (float)xv[2], v3 = (float)xv[3];
    float s = v0 + v1 + v2 + v3;
    float s2 = v0 * v0 + v1 * v1 + v2 * v2 + v3 * v3;
#pragma unroll
    for (int msk = 1; msk < 64; msk <<= 1) {
      s += __shfl_xor(s, msk);
      s2 += __shfl_xor(s2, msk);
    }
    float mean = s * (1.f / 256.f);
    float var = s2 * (1.f / 256.f) - mean * mean;
    float rs = rsqrtf(var + 1e-5f);
    bf16x4 o;
    o[0] = (bf16_t)((v0 - mean) * rs * g4.x + b4.x);
    o[1] = (bf16_t)((v1 - mean) * rs * g4.y + b4.y);
    o[2] = (bf16_t)((v2 - mean) * rs * g4.z + b4.z);
    o[3] = (bf16_t)((v3 - mean) * rs * g4.w + b4.w);
    // swizzled store: 8-el chunk index (lane>>1) ^ (row&7), half-chunk (lane&1)
    *(bf16x4*)(ys + r * 256 + ((((lane >> 1) ^ (r & 7)) << 3) | ((lane & 1) << 2))) = o;
  }
  __syncthreads();

  f32x4 acc2[2][4] = {};  // FC2 acc: 32 tok x 64 n per wave

  for (int hc = 0; hc < 8; ++hc) {
    int p = hc & 1;
    // ---- FC1' chunk: h^T[128 hid][32 tok]; wave owns 32 hid rows ----
    f32x4 acc1[2][2] = {};
#pragma unroll
    for (int kk = 0; kk < 8; ++kk) {
      bf16x8 xf[2], yf[2];
#pragma unroll
      for (int mh = 0; mh < 2; ++mh)
        xf[mh] = *(const bf16x8*)(w1 + (long)(hc * 128 + wv * 32 + mh * 16 + lr) * 256 + kk * 32 + lk);
#pragma unroll
      for (int nt = 0; nt < 2; ++nt)
        yf[nt] = *(const bf16x8*)(ys + (nt * 16 + lr) * 256 + (((kk * 4 + g) ^ (lr & 7)) << 3));
#pragma unroll
      for (int mh = 0; mh < 2; ++mh)
#pragma unroll
        for (int nt = 0; nt < 2; ++nt)
          acc1[mh][nt] = MFMA(xf[mh], yf[nt], acc1[mh][nt], 0, 0, 0);
    }
    // bias + exact GeLU -> swizzled hs[p] (bf16x4, hidden-consecutive)
#pragma unroll
    for (int mh = 0; mh < 2; ++mh) {
      float4 bb = *(const float4*)(b1 + hc * 128 + wv * 32 + mh * 16 + 4 * g);
#pragma unroll
      for (int nt = 0; nt < 2; ++nt) {
        bf16x4 o;
#pragma unroll
        for (int r = 0; r < 4; ++r) {
          float val = acc1[mh][nt][r] + ((const float*)&bb)[r];
          o[r] = (bf16_t)(0.5f * val * (1.0f + erff(val * 0.70710678118654752f)));
        }
        int chunk = (wv * 4 + mh * 2 + (g >> 1)) ^ (lr & 7);
        *(bf16x4*)(hs[p] + (nt * 16 + lr) * 128 + (chunk << 3) + ((g & 1) << 2)) = o;
      }
    }
    __syncthreads();  // hs[p] complete (only barrier per chunk)
    // ---- FC2 accumulate: out[tok][n] += h[tok][k]*w2[n][k], k = this 128-chunk ----
#pragma unroll
    for (int kk = 0; kk < 4; ++kk) {
      bf16x8 ah[2], bw[4];
#pragma unroll
      for (int mf = 0; mf < 2; ++mf)
        ah[mf] = *(const bf16x8*)(hs[p] + (mf * 16 + lr) * 128 + (((kk * 4 + g) ^ (lr & 7)) << 3));
#pragma unroll
      for (int nf = 0; nf < 4; ++nf)
        bw[nf] = *(const bf16x8*)(w2 + (long)(wv * 64 + nf * 16 + lr) * 1024 + hc * 128 + kk * 32 + lk);
#pragma unroll
      for (int mf = 0; mf < 2; ++mf)
#pragma unroll
        for (int nf = 0; nf < 4; ++nf)
          acc2[mf][nf] = MFMA(ah[mf], bw[nf], acc2[mf][nf], 0, 0, 0);
    }
  }

  // ---- epilogue: out = x1 + b2 + mlp (sole writer of d_out) ----
#pragma unroll
  for (int mf = 0; mf < 2; ++mf)
#pragma unroll
    for (int nf = 0; nf < 4; ++nf) {
      int n = wv * 64 + nf * 16 + lr;
      float bn = b2[n];
#pragma unroll
      for (int r = 0; r < 4; ++r) {
        long row = m0 + mf * 16 + 4 * g + r;
        out[row * 256 + n] = acc2[mf][nf][r] + bn + (float)x1b[row * 256 + n];
      }
    }
}

// ---------------- per-window attention: 4 waves x 2 heads ----------------
__global__ __launch_bounds__(256) void attn_kernel(const bf16_t* __restrict__ qkv,
                                                   const float* __restrict__ rpb,
                                                   bf16_t* __restrict__ attn_out) {
  __shared__ float rpb_s[1800];       // 225 x 8
  __shared__ bf16_t P[4][64][72];     // +8 pad: 144B stride -> 2-way (free)
  int tid = threadIdx.x, lane = tid & 63, wv = tid >> 6;
  long b_ = blockIdx.x;
  for (int i = tid; i < 1800; i += 256) rpb_s[i] = rpb[i];
  __syncthreads();
  const bf16_t* q = qkv;
  const bf16_t* k = qkv + QKV_SEG;
  const bf16_t* vt = qkv + 2 * QKV_SEG;
  int lr = lane & 15, lk = (lane >> 4) * 8, g = lane >> 4;
  const float scale = 0.17677669529663688f;  // 32^-0.5

  for (int hh = 0; hh < 2; ++hh) {
    int head = wv * 2 + hh;
    long base = (b_ * 8 + head) * 2048;
    bf16x8 af[4], bfr[4];
#pragma unroll
    for (int mf = 0; mf < 4; ++mf)
      af[mf] = *(const bf16x8*)(q + base + (mf * 16 + lr) * 32 + lk);
#pragma unroll
    for (int nf = 0; nf < 4; ++nf)
      bfr[nf] = *(const bf16x8*)(k + base + (nf * 16 + lr) * 32 + lk);
    f32x4 S[4][4] = {};
#pragma unroll
    for (int mf = 0; mf < 4; ++mf)
#pragma unroll
      for (int nf = 0; nf < 4; ++nf)
        S[mf][nf] = MFMA(af[mf], bfr[nf], S[mf][nf], 0, 0, 0);
#pragma unroll
    for (int mf = 0; mf < 4; ++mf)
#pragma unroll
      for (int nf = 0; nf < 4; ++nf)
#pragma unroll
        for (int r = 0; r < 4; ++r) {
          int i = mf * 16 + 4 * g + r, j = nf * 16 + lr;
          int rel = ((i >> 3) - (j >> 3) + 7) * 15 + ((i & 7) - (j & 7) + 7);
          S[mf][nf][r] = S[mf][nf][r] * scale + rpb_s[rel * 8 + head];
        }
#pragma unroll
    for (int mf = 0; mf < 4; ++mf) {
#pragma unroll
      for (int r = 0; r < 4; ++r) {
        float mx = fmaxf(fmaxf(S[mf][0][r], S[mf][1][r]), fmaxf(S[mf][2][r], S[mf][3][r]));
#pragma unroll
        for (int msk = 1; msk < 16; msk <<= 1) mx = fmaxf(mx, __shfl_xor(mx, msk));
        float sm = 0.f;
#pragma unroll
        for (int nf = 0; nf < 4; ++nf) {
          float e = __expf(S[mf][nf][r] - mx);
          S[mf][nf][r] = e;
          sm += e;
        }
#pragma unroll
        for (int msk = 1; msk < 16; msk <<= 1) sm += __shfl_xor(sm, msk);
        float is = 1.f / sm;
        int i = mf * 16 + 4 * g + r;
#pragma unroll
        for (int nf = 0; nf < 4; ++nf) P[wv][i][nf * 16 + lr] = (bf16_t)(S[mf][nf][r] * is);
      }
    }
    f32x4 O[4][2] = {};
#pragma unroll
    for (int ks = 0; ks < 2; ++ks) {
      int j0 = ks * 32;
      bf16x8 pa[4], vb[2];
#pragma unroll
      for (int mf = 0; mf < 4; ++mf) pa[mf] = *(const bf16x8*)(&P[wv][mf * 16 + lr][j0 + lk]);
#pragma unroll
      for (int nf = 0; nf < 2; ++nf)
        vb[nf] = *(const bf16x8*)(vt + base + (nf * 16 + lr) * 64 + j0 + lk);
#pragma unroll
      for (int mf = 0; mf < 4; ++mf)
#pragma unroll
        for (int nf = 0; nf < 2; ++nf)
          O[mf][nf] = MFMA(pa[mf], vb[nf], O[mf][nf], 0, 0, 0);
    }
#pragma unroll
    for (int mf = 0; mf < 4; ++mf)
#pragma unroll
      for (int nf = 0; nf < 2; ++nf)
#pragma unroll
        for (int r = 0; r < 4; ++r) {
          int i = mf * 16 + 4 * g + r, d = nf * 16 + lr;
          attn_out[(b_ * 64 + i) * 256 + head * 32 + d] = (bf16_t)O[mf][nf][r];
        }
  }
}

extern "C" void kernel_launch(void* const* d_in, const int* in_sizes, int n_in,
                              void* d_out, int out_size, void* d_ws, size_t ws_size,
                              hipStream_t stream) {
  const float* x = (const float*)d_in[0];
  const float* n1w = (const float*)d_in[1];
  const float* n1b = (const float*)d_in[2];
  const float* qkv_w = (const float*)d_in[3];
  const float* qkv_b = (const float*)d_in[4];
  const float* rpb = (const float*)d_in[5];
  const float* proj_w = (const float*)d_in[6];
  const float* proj_b = (const float*)d_in[7];
  const float* n2w = (const float*)d_in[8];
  const float* n2b = (const float*)d_in[9];
  const float* fc1_w = (const float*)d_in[10];
  const float* fc1_b = (const float*)d_in[11];
  const float* fc2_w = (const float*)d_in[12];
  const float* fc2_b = (const float*)d_in[13];
  float* out = (float*)d_out;

  char* ws = (char*)d_ws;
  bf16_t* bufA = (bf16_t*)ws;                       // qkv (201MB)
  bf16_t* x1b = (bf16_t*)(ws + 201326592L);         // x1 bf16 (67MB)
  bf16_t* bufB = (bf16_t*)(ws + 268435456L);        // xw / attn_out (67MB)
  bf16_t* wq = (bf16_t*)(ws + 335544320L);          // bf16 weights (1.6MB)
  bf16_t* wp = wq + 196608;
  bf16_t* w1 = wp + 65536;
  bf16_t* w2 = w1 + 262144;

  // weights -> bf16
  cvt_kernel<<<192, 256, 0, stream>>>(qkv_w, wq);
  cvt_kernel<<<64, 256, 0, stream>>>(proj_w, wp);
  cvt_kernel<<<256, 256, 0, stream>>>(fc1_w, w1);
  cvt_kernel<<<256, 256, 0, stream>>>(fc2_w, w2);

  // LN1 + shift + window partition -> xw (bufB)
  ln_kernel<<<32768, 256, 0, stream>>>(x, n1w, n1b, bufB);
  // QKV GEMM -> q/k/v_t (bufA)
  gemm_kernel<0><<<dim3(6, 1024), 256, 0, stream>>>(bufB, wq, qkv_b, 256, bufA, nullptr);
  // window attention -> attn_out (bufB)
  attn_kernel<<<2048, 256, 0, stream>>>(bufA, rpb, bufB);
  // proj + reverse shift + residual(x) -> x1 bf16
  gemm_kernel<1><<<dim3(2, 1024), 256, 0, stream>>>(bufB, wp, proj_b, 256, x1b, x);
  // fused LN2 + FC1 + GeLU + FC2 + residual -> d_out (fp32, sole writer)
  mlp_kernel<<<4096, 256, 0, stream>>>(x1b, out, n2w, n2b, w1, fc1_b, w2, fc2_b);
}

// Round 12
// 621.315 us; speedup vs baseline: 1.9089x; 1.2781x over previous
//
#include <hip/hip_runtime.h>

typedef __bf16 bf16_t;
typedef __bf16 bf16x4 __attribute__((ext_vector_type(4)));
typedef __bf16 bf16x8 __attribute__((ext_vector_type(8)));
typedef float f32x4 __attribute__((ext_vector_type(4)));

#define QKV_SEG 33554432L  // elements per q/k/v segment: 2048 win * 8 heads * 64 tok * 32 d

#define GLDS(gp, lp)                                                                   \
  __builtin_amdgcn_global_load_lds((const __attribute__((address_space(1))) void*)(gp), \
                                   (__attribute__((address_space(3))) void*)(lp), 16, 0, 0)
#define BAR __builtin_amdgcn_s_barrier()
#define SCHED0 __builtin_amdgcn_sched_barrier(0)
#define MFMA __builtin_amdgcn_mfma_f32_16x16x32_bf16

// ---------------- weight fp32 -> bf16 convert ----------------
__global__ __launch_bounds__(256) void cvt_kernel(const float* __restrict__ src,
                                                  bf16_t* __restrict__ dst) {
  int i = (blockIdx.x * 256 + threadIdx.x) * 4;
  float4 v = *(const float4*)(src + i);
  bf16x4 o;
  o[0] = (bf16_t)v.x; o[1] = (bf16_t)v.y; o[2] = (bf16_t)v.z; o[3] = (bf16_t)v.w;
  *(bf16x4*)(dst + i) = o;
}

// ---------------- LayerNorm1 + shift + window-partition gather ----------------
__global__ __launch_bounds__(256) void ln_kernel(const float* __restrict__ src,
                                                 const float* __restrict__ gw,
                                                 const float* __restrict__ gb,
                                                 bf16_t* __restrict__ dst) {
  int lane = threadIdx.x & 63, wv = threadIdx.x >> 6;
  long m = (long)blockIdx.x * 4 + wv;  // dest row (window-token order)
  long b_ = m >> 6; int tok = (int)(m & 63);
  int bb = (int)(b_ >> 8), win = (int)(b_ & 255);
  int wh = win >> 4, ww = win & 15;
  int ii = tok >> 3, jj = tok & 7;
  int hh = (wh * 8 + ii + 4) & 127, wp = (ww * 8 + jj + 4) & 127;
  long srow = ((long)bb << 14) + (hh << 7) + wp;

  float4 v = *(const float4*)(src + srow * 256 + lane * 4);
  float s = v.x + v.y + v.z + v.w;
  float s2 = v.x * v.x + v.y * v.y + v.z * v.z + v.w * v.w;
#pragma unroll
  for (int msk = 1; msk < 64; msk <<= 1) {
    s += __shfl_xor(s, msk);
    s2 += __shfl_xor(s2, msk);
  }
  float mean = s * (1.f / 256.f);
  float var = s2 * (1.f / 256.f) - mean * mean;
  float rs = rsqrtf(var + 1e-5f);
  float4 g4 = *(const float4*)(gw + lane * 4);
  float4 b4 = *(const float4*)(gb + lane * 4);
  bf16x4 o;
  o[0] = (bf16_t)((v.x - mean) * rs * g4.x + b4.x);
  o[1] = (bf16_t)((v.y - mean) * rs * g4.y + b4.y);
  o[2] = (bf16_t)((v.z - mean) * rs * g4.z + b4.z);
  o[3] = (bf16_t)((v.w - mean) * rs * g4.w + b4.w);
  *(bf16x4*)(dst + m * 256 + lane * 4) = o;
}

// ---------------- GEMM (QKV / proj): BK=64 depth-2, counted vmcnt, XCD swizzle ----------------
// EPI 0: qkv scatter -> q/k/v_t bf16
// EPI 1: proj + reverse-shift + residual(x fp32) -> x1 bf16 (out_bf)
template <int EPI>
__global__ __launch_bounds__(256) void gemm_kernel(const bf16_t* __restrict__ A,
                                                   const bf16_t* __restrict__ Bw,
                                                   const float* __restrict__ bias, int K,
                                                   bf16_t* __restrict__ out_bf,
                                                   const float* resid) {
  __shared__ __align__(16) bf16_t As[2][8192];  // [buf][128*64]
  __shared__ __align__(16) bf16_t Bs[2][8192];
  int tid = threadIdx.x;
  int lane = tid & 63, wv = tid >> 6;
  int wm = wv >> 1, wn = wv & 1;

  int GX = gridDim.x, GY = gridDim.y;
  int flat = blockIdx.x + blockIdx.y * GX;
  int xcd = flat & 7, ii = flat >> 3;
  int iq = ii / GX;
  int by = xcd * (GY >> 3) + iq;
  int bx = ii - iq * GX;
  long m0 = (long)by * 128;
  int n0 = bx * 128;
  int lr = lane & 15, g = lane >> 4;

  int csw = (((lane & 7) ^ (lane >> 3)) << 3);
  const bf16_t* gA = A + (m0 + wv * 32 + (lane >> 3)) * K + csw;
  const bf16_t* gB = Bw + (long)(n0 + wv * 32 + (lane >> 3)) * K + csw;

  f32x4 acc[4][4] = {};

#define STAGE(buf, k0)                                                    \
  do {                                                                    \
    _Pragma("unroll") for (int s = 0; s < 4; ++s) {                       \
      GLDS(gA + (long)s * 8 * K + (k0), As[buf] + wv * 2048 + s * 512);   \
      GLDS(gB + (long)s * 8 * K + (k0), Bs[buf] + wv * 2048 + s * 512);   \
    }                                                                     \
  } while (0)

  int nt = K >> 6;
  STAGE(0, 0);
  for (int t = 0; t < nt; ++t) {
    int tb = t & 1;
    if (t + 1 < nt) {
      STAGE(tb ^ 1, (t + 1) << 6);
      asm volatile("s_waitcnt vmcnt(8)" ::: "memory");
    } else {
      asm volatile("s_waitcnt vmcnt(0)" ::: "memory");
    }
    BAR;
    SCHED0;
#pragma unroll
    for (int kk = 0; kk < 2; ++kk) {
      bf16x8 af[4], bfr[4];
#pragma unroll
      for (int mf = 0; mf < 4; ++mf)
        af[mf] = *(const bf16x8*)(As[tb] + (wm * 64 + mf * 16 + lr) * 64 +
                                  (((kk * 4 + g) ^ (lr & 7)) << 3));
#pragma unroll
      for (int nf = 0; nf < 4; ++nf)
        bfr[nf] = *(const bf16x8*)(Bs[tb] + (wn * 64 + nf * 16 + lr) * 64 +
                                   (((kk * 4 + g) ^ (lr & 7)) << 3));
#pragma unroll
      for (int mf = 0; mf < 4; ++mf)
#pragma unroll
        for (int nf = 0; nf < 4; ++nf)
          acc[mf][nf] = MFMA(af[mf], bfr[nf], acc[mf][nf], 0, 0, 0);
    }
    BAR;
  }
#undef STAGE

#pragma unroll
  for (int mf = 0; mf < 4; ++mf) {
#pragma unroll
    for (int nf = 0; nf < 4; ++nf) {
      long mb = m0 + wm * 64 + mf * 16 + 4 * g;
      int n = n0 + wn * 64 + nf * 16 + lr;
      float bn = bias[n];
      if (EPI == 0) {
        long b_ = mb >> 6;
        int tok = (int)(mb & 63);
        int which = n >> 8, rem = n & 255, head = rem >> 5, d = rem & 31;
        if (which == 2) {
          bf16x4 o;
#pragma unroll
          for (int r = 0; r < 4; ++r) o[r] = (bf16_t)(acc[mf][nf][r] + bn);
          *(bf16x4*)(out_bf + 2 * QKV_SEG + ((b_ * 8 + head) * 32 + d) * 64 + tok) = o;
        } else {
          long base = (long)which * QKV_SEG + ((b_ * 8 + head) * 64 + tok) * 32 + d;
#pragma unroll
          for (int r = 0; r < 4; ++r) out_bf[base + r * 32] = (bf16_t)(acc[mf][nf][r] + bn);
        }
      } else {
#pragma unroll
        for (int r = 0; r < 4; ++r) {
          long m = mb + r;
          long b_ = m >> 6; int tok = (int)(m & 63);
          int bb = (int)(b_ >> 8), win = (int)(b_ & 255);
          int wh = win >> 4, ww = win & 15;
          int jj0 = tok >> 3, jj = tok & 7;
          int hh = (wh * 8 + jj0 + 4) & 127, wp = (ww * 8 + jj + 4) & 127;
          long dst = (((long)bb << 14) + (hh << 7) + wp) * 256 + n;
          out_bf[dst] = (bf16_t)(acc[mf][nf][r] + bn + resid[dst]);
        }
      }
    }
  }
}

// ---------------- fused MLP v4: LN2 + FC1 + GeLU + FC2 + residual ----------------
// 64 tokens/block (grid 2048), 4 waves, 51KB LDS -> 3 blocks/CU (R8 geometry).
// KEY CHANGE vs R8: weight fragments are BATCH-PREFETCHED into register arrays
// (4-kk batches for FC1, 2-kk for FC2) BEFORE the consume loop -> 8 independent
// global loads in flight per wave (compiler emits counted waitcnt), one L2
// latency per batch instead of per kk.
__global__ __launch_bounds__(256, 3) void mlp_kernel(const bf16_t* __restrict__ x1b,
                                                     float* __restrict__ out,
                                                     const float* __restrict__ gw,
                                                     const float* __restrict__ gb,
                                                     const bf16_t* __restrict__ w1,
                                                     const float* __restrict__ b1,
                                                     const bf16_t* __restrict__ w2,
                                                     const float* __restrict__ b2) {
  __shared__ __align__(16) bf16_t ys[64][264];  // LN output (+8 pad)
  __shared__ __align__(16) bf16_t hs[64][136];  // h chunk [tok][hid128] (+8 pad)
  int tid = threadIdx.x, lane = tid & 63, wv = tid >> 6;
  long m0 = (long)blockIdx.x * 64;
  int lr = lane & 15, lk = (lane >> 4) * 8, g = lane >> 4;

  // ---- LN2 (bf16 in): 16 rows per wave ----
  float4 g4 = *(const float4*)(gw + lane * 4);
  float4 b4 = *(const float4*)(gb + lane * 4);
#pragma unroll
  for (int i = 0; i < 16; ++i) {
    int r = wv * 16 + i;
    bf16x4 xv = *(const bf16x4*)(x1b + (m0 + r) * 256 + lane * 4);
    float v0 = (float)xv[0], v1 = (float)xv[1], v2 = (float)xv[2], v3 = (float)xv[3];
    float s = v0 + v1 + v2 + v3;
    float s2 = v0 * v0 + v1 * v1 + v2 * v2 + v3 * v3;
#pragma unroll
    for (int msk = 1; msk < 64; msk <<= 1) {
      s += __shfl_xor(s, msk);
      s2 += __shfl_xor(s2, msk);
    }
    float mean = s * (1.f / 256.f);
    float var = s2 * (1.f / 256.f) - mean * mean;
    float rs = rsqrtf(var + 1e-5f);
    bf16x4 o;
    o[0] = (bf16_t)((v0 - mean) * rs * g4.x + b4.x);
    o[1] = (bf16_t)((v1 - mean) * rs * g4.y + b4.y);
    o[2] = (bf16_t)((v2 - mean) * rs * g4.z + b4.z);
    o[3] = (bf16_t)((v3 - mean) * rs * g4.w + b4.w);
    *(bf16x4*)(&ys[r][lane * 4]) = o;
  }
  __syncthreads();

  f32x4 acc2[4][4] = {};  // FC2: 64 tok x 64 n per wave (n = wv*64..)

  for (int hc = 0; hc < 8; ++hc) {
    // ---- FC1' chunk: h^T[128 hid][64 tok]; wave owns 32 hid rows ----
    f32x4 acc1[2][4] = {};
#pragma unroll
    for (int half = 0; half < 2; ++half) {
      // batch-issue 8 independent w1 loads (4 kk x 2 mh) into regs
      bf16x8 xf[4][2];
#pragma unroll
      for (int kb = 0; kb < 4; ++kb)
#pragma unroll
        for (int mh = 0; mh < 2; ++mh)
          xf[kb][mh] = *(const bf16x8*)(w1 + (long)(hc * 128 + wv * 32 + mh * 16 + lr) * 256 +
                                        (half * 4 + kb) * 32 + lk);
#pragma unroll
      for (int kb = 0; kb < 4; ++kb) {
        bf16x8 yf[4];
#pragma unroll
        for (int nt = 0; nt < 4; ++nt)
          yf[nt] = *(const bf16x8*)(&ys[nt * 16 + lr][(half * 4 + kb) * 32 + lk]);
#pragma unroll
        for (int mh = 0; mh < 2; ++mh)
#pragma unroll
          for (int nt = 0; nt < 4; ++nt)
            acc1[mh][nt] = MFMA(xf[kb][mh], yf[nt], acc1[mh][nt], 0, 0, 0);
      }
    }
    // bias + exact GeLU -> hs[tok][hid] (bf16x4, hidden-consecutive)
#pragma unroll
    for (int mh = 0; mh < 2; ++mh) {
      float4 bb = *(const float4*)(b1 + hc * 128 + wv * 32 + mh * 16 + 4 * g);
#pragma unroll
      for (int nt = 0; nt < 4; ++nt) {
        bf16x4 o;
#pragma unroll
        for (int r = 0; r < 4; ++r) {
          float val = acc1[mh][nt][r] + ((const float*)&bb)[r];
          o[r] = (bf16_t)(0.5f * val * (1.0f + erff(val * 0.70710678118654752f)));
        }
        *(bf16x4*)(&hs[nt * 16 + lr][wv * 32 + mh * 16 + 4 * g]) = o;
      }
    }
    __syncthreads();
    // ---- FC2 accumulate: out[tok][n] += h[tok][k]*w2[n][k], k = this 128-chunk ----
#pragma unroll
    for (int half = 0; half < 2; ++half) {
      // batch-issue 8 independent w2 loads (2 kk x 4 nf) into regs
      bf16x8 bw[2][4];
#pragma unroll
      for (int kb = 0; kb < 2; ++kb)
#pragma unroll
        for (int nf = 0; nf < 4; ++nf)
          bw[kb][nf] = *(const bf16x8*)(w2 + (long)(wv * 64 + nf * 16 + lr) * 1024 + hc * 128 +
                                        (half * 2 + kb) * 32 + lk);
#pragma unroll
      for (int kb = 0; kb < 2; ++kb) {
        bf16x8 ah[4];
#pragma unroll
        for (int mf = 0; mf < 4; ++mf)
          ah[mf] = *(const bf16x8*)(&hs[mf * 16 + lr][(half * 2 + kb) * 32 + lk]);
#pragma unroll
        for (int mf = 0; mf < 4; ++mf)
#pragma unroll
          for (int nf = 0; nf < 4; ++nf)
            acc2[mf][nf] = MFMA(ah[mf], bw[kb][nf], acc2[mf][nf], 0, 0, 0);
      }
    }
    __syncthreads();  // hs reads done before next chunk overwrites
  }

  // ---- epilogue: out = x1 + b2 + mlp (sole writer of d_out) ----
#pragma unroll
  for (int mf = 0; mf < 4; ++mf)
#pragma unroll
    for (int nf = 0; nf < 4; ++nf) {
      int n = wv * 64 + nf * 16 + lr;
      float bn = b2[n];
#pragma unroll
      for (int r = 0; r < 4; ++r) {
        long row = m0 + mf * 16 + 4 * g + r;
        out[row * 256 + n] = acc2[mf][nf][r] + bn + (float)x1b[row * 256 + n];
      }
    }
}

// ---------------- per-window attention: 4 waves x 2 heads ----------------
__global__ __launch_bounds__(256) void attn_kernel(const bf16_t* __restrict__ qkv,
                                                   const float* __restrict__ rpb,
                                                   bf16_t* __restrict__ attn_out) {
  __shared__ float rpb_s[1800];       // 225 x 8
  __shared__ bf16_t P[4][64][72];     // +8 pad
  int tid = threadIdx.x, lane = tid & 63, wv = tid >> 6;
  long b_ = blockIdx.x;
  for (int i = tid; i < 1800; i += 256) rpb_s[i] = rpb[i];
  __syncthreads();
  const bf16_t* q = qkv;
  const bf16_t* k = qkv + QKV_SEG;
  const bf16_t* vt = qkv + 2 * QKV_SEG;
  int lr = lane & 15, lk = (lane >> 4) * 8, g = lane >> 4;
  const float scale = 0.17677669529663688f;  // 32^-0.5

  for (int hh = 0; hh < 2; ++hh) {
    int head = wv * 2 + hh;
    long base = (b_ * 8 + head) * 2048;
    bf16x8 af[4], bfr[4];
#pragma unroll
    for (int mf = 0; mf < 4; ++mf)
      af[mf] = *(const bf16x8*)(q + base + (mf * 16 + lr) * 32 + lk);
#pragma unroll
    for (int nf = 0; nf < 4; ++nf)
      bfr[nf] = *(const bf16x8*)(k + base + (nf * 16 + lr) * 32 + lk);
    f32x4 S[4][4] = {};
#pragma unroll
    for (int mf = 0; mf < 4; ++mf)
#pragma unroll
      for (int nf = 0; nf < 4; ++nf)
        S[mf][nf] = MFMA(af[mf], bfr[nf], S[mf][nf], 0, 0, 0);
#pragma unroll
    for (int mf = 0; mf < 4; ++mf)
#pragma unroll
      for (int nf = 0; nf < 4; ++nf)
#pragma unroll
        for (int r = 0; r < 4; ++r) {
          int i = mf * 16 + 4 * g + r, j = nf * 16 + lr;
          int rel = ((i >> 3) - (j >> 3) + 7) * 15 + ((i & 7) - (j & 7) + 7);
          S[mf][nf][r] = S[mf][nf][r] * scale + rpb_s[rel * 8 + head];
        }
#pragma unroll
    for (int mf = 0; mf < 4; ++mf) {
#pragma unroll
      for (int r = 0; r < 4; ++r) {
        float mx = fmaxf(fmaxf(S[mf][0][r], S[mf][1][r]), fmaxf(S[mf][2][r], S[mf][3][r]));
#pragma unroll
        for (int msk = 1; msk < 16; msk <<= 1) mx = fmaxf(mx, __shfl_xor(mx, msk));
        float sm = 0.f;
#pragma unroll
        for (int nf = 0; nf < 4; ++nf) {
          float e = __expf(S[mf][nf][r] - mx);
          S[mf][nf][r] = e;
          sm += e;
        }
#pragma unroll
        for (int msk = 1; msk < 16; msk <<= 1) sm += __shfl_xor(sm, msk);
        float is = 1.f / sm;
        int i = mf * 16 + 4 * g + r;
#pragma unroll
        for (int nf = 0; nf < 4; ++nf) P[wv][i][nf * 16 + lr] = (bf16_t)(S[mf][nf][r] * is);
      }
    }
    f32x4 O[4][2] = {};
#pragma unroll
    for (int ks = 0; ks < 2; ++ks) {
      int j0 = ks * 32;
      bf16x8 pa[4], vb[2];
#pragma unroll
      for (int mf = 0; mf < 4; ++mf) pa[mf] = *(const bf16x8*)(&P[wv][mf * 16 + lr][j0 + lk]);
#pragma unroll
      for (int nf = 0; nf < 2; ++nf)
        vb[nf] = *(const bf16x8*)(vt + base + (nf * 16 + lr) * 64 + j0 + lk);
#pragma unroll
      for (int mf = 0; mf < 4; ++mf)
#pragma unroll
        for (int nf = 0; nf < 2; ++nf)
          O[mf][nf] = MFMA(pa[mf], vb[nf], O[mf][nf], 0, 0, 0);
    }
#pragma unroll
    for (int mf = 0; mf < 4; ++mf)
#pragma unroll
      for (int nf = 0; nf < 2; ++nf)
#pragma unroll
        for (int r = 0; r < 4; ++r) {
          int i = mf * 16 + 4 * g + r, d = nf * 16 + lr;
          attn_out[(b_ * 64 + i) * 256 + head * 32 + d] = (bf16_t)O[mf][nf][r];
        }
  }
}

extern "C" void kernel_launch(void* const* d_in, const int* in_sizes, int n_in,
                              void* d_out, int out_size, void* d_ws, size_t ws_size,
                              hipStream_t stream) {
  const float* x = (const float*)d_in[0];
  const float* n1w = (const float*)d_in[1];
  const float* n1b = (const float*)d_in[2];
  const float* qkv_w = (const float*)d_in[3];
  const float* qkv_b = (const float*)d_in[4];
  const float* rpb = (const float*)d_in[5];
  const float* proj_w = (const float*)d_in[6];
  const float* proj_b = (const float*)d_in[7];
  const float* n2w = (const float*)d_in[8];
  const float* n2b = (const float*)d_in[9];
  const float* fc1_w = (const float*)d_in[10];
  const float* fc1_b = (const float*)d_in[11];
  const float* fc2_w = (const float*)d_in[12];
  const float* fc2_b = (const float*)d_in[13];
  float* out = (float*)d_out;

  char* ws = (char*)d_ws;
  bf16_t* bufA = (bf16_t*)ws;                       // qkv (201MB)
  bf16_t* x1b = (bf16_t*)(ws + 201326592L);         // x1 bf16 (67MB)
  bf16_t* bufB = (bf16_t*)(ws + 268435456L);        // xw / attn_out (67MB)
  bf16_t* wq = (bf16_t*)(ws + 335544320L);          // bf16 weights (1.6MB)
  bf16_t* wp = wq + 196608;
  bf16_t* w1 = wp + 65536;
  bf16_t* w2 = w1 + 262144;

  // weights -> bf16
  cvt_kernel<<<192, 256, 0, stream>>>(qkv_w, wq);
  cvt_kernel<<<64, 256, 0, stream>>>(proj_w, wp);
  cvt_kernel<<<256, 256, 0, stream>>>(fc1_w, w1);
  cvt_kernel<<<256, 256, 0, stream>>>(fc2_w, w2);

  // LN1 + shift + window partition -> xw (bufB)
  ln_kernel<<<32768, 256, 0, stream>>>(x, n1w, n1b, bufB);
  // QKV GEMM -> q/k/v_t (bufA)
  gemm_kernel<0><<<dim3(6, 1024), 256, 0, stream>>>(bufB, wq, qkv_b, 256, bufA, nullptr);
  // window attention -> attn_out (bufB)
  attn_kernel<<<2048, 256, 0, stream>>>(bufA, rpb, bufB);
  // proj + reverse shift + residual(x) -> x1 bf16
  gemm_kernel<1><<<dim3(2, 1024), 256, 0, stream>>>(bufB, wp, proj_b, 256, x1b, x);
  // fused LN2 + FC1 + GeLU + FC2 + residual -> d_out (fp32, sole writer)
  mlp_kernel<<<2048, 256, 0, stream>>>(x1b, out, n2w, n2b, w1, fc1_b, w2, fc2_b);
}

// Round 13
// 602.437 us; speedup vs baseline: 1.9687x; 1.0313x over previous
//
#include <hip/hip_runtime.h>

typedef __bf16 bf16_t;
typedef __bf16 bf16x4 __attribute__((ext_vector_type(4)));
typedef __bf16 bf16x8 __attribute__((ext_vector_type(8)));
typedef float f32x4 __attribute__((ext_vector_type(4)));

#define QKV_SEG 33554432L  // elements per q/k/v segment: 2048 win * 8 heads * 64 tok * 32 d

#define GLDS(gp, lp)                                                                   \
  __builtin_amdgcn_global_load_lds((const __attribute__((address_space(1))) void*)(gp), \
                                   (__attribute__((address_space(3))) void*)(lp), 16, 0, 0)
#define BAR __builtin_amdgcn_s_barrier()
#define SCHED0 __builtin_amdgcn_sched_barrier(0)
#define MFMA __builtin_amdgcn_mfma_f32_16x16x32_bf16

// tanh-form GeLU: 0.5u(1+tanh(.7979(u+.044715u^3))) = u - u/(exp(2c)+1)
// max |dev from exact-erf gelu| ~3e-3, below bf16 rounding of h.
__device__ inline float gelu_f(float u) {
  float c2 = 1.5957691216057308f * (u + 0.044715f * u * u * u);
  return u - u / (__expf(c2) + 1.0f);
}

// ---------------- weight fp32 -> bf16 convert ----------------
__global__ __launch_bounds__(256) void cvt_kernel(const float* __restrict__ src,
                                                  bf16_t* __restrict__ dst) {
  int i = (blockIdx.x * 256 + threadIdx.x) * 4;
  float4 v = *(const float4*)(src + i);
  bf16x4 o;
  o[0] = (bf16_t)v.x; o[1] = (bf16_t)v.y; o[2] = (bf16_t)v.z; o[3] = (bf16_t)v.w;
  *(bf16x4*)(dst + i) = o;
}

// ---------------- LayerNorm1 + shift + window-partition gather ----------------
__global__ __launch_bounds__(256) void ln_kernel(const float* __restrict__ src,
                                                 const float* __restrict__ gw,
                                                 const float* __restrict__ gb,
                                                 bf16_t* __restrict__ dst) {
  int lane = threadIdx.x & 63, wv = threadIdx.x >> 6;
  long m = (long)blockIdx.x * 4 + wv;  // dest row (window-token order)
  long b_ = m >> 6; int tok = (int)(m & 63);
  int bb = (int)(b_ >> 8), win = (int)(b_ & 255);
  int wh = win >> 4, ww = win & 15;
  int ii = tok >> 3, jj = tok & 7;
  int hh = (wh * 8 + ii + 4) & 127, wp = (ww * 8 + jj + 4) & 127;
  long srow = ((long)bb << 14) + (hh << 7) + wp;

  float4 v = *(const float4*)(src + srow * 256 + lane * 4);
  float s = v.x + v.y + v.z + v.w;
  float s2 = v.x * v.x + v.y * v.y + v.z * v.z + v.w * v.w;
#pragma unroll
  for (int msk = 1; msk < 64; msk <<= 1) {
    s += __shfl_xor(s, msk);
    s2 += __shfl_xor(s2, msk);
  }
  float mean = s * (1.f / 256.f);
  float var = s2 * (1.f / 256.f) - mean * mean;
  float rs = rsqrtf(var + 1e-5f);
  float4 g4 = *(const float4*)(gw + lane * 4);
  float4 b4 = *(const float4*)(gb + lane * 4);
  bf16x4 o;
  o[0] = (bf16_t)((v.x - mean) * rs * g4.x + b4.x);
  o[1] = (bf16_t)((v.y - mean) * rs * g4.y + b4.y);
  o[2] = (bf16_t)((v.z - mean) * rs * g4.z + b4.z);
  o[3] = (bf16_t)((v.w - mean) * rs * g4.w + b4.w);
  *(bf16x4*)(dst + m * 256 + lane * 4) = o;
}

// ---------------- GEMM (QKV / proj): BK=64 depth-2, counted vmcnt, XCD swizzle ----------------
// EPI 0: qkv scatter -> q/k/v_t bf16
// EPI 1: proj + reverse-shift + residual(x fp32) -> x1 bf16 (out_bf)
template <int EPI>
__global__ __launch_bounds__(256) void gemm_kernel(const bf16_t* __restrict__ A,
                                                   const bf16_t* __restrict__ Bw,
                                                   const float* __restrict__ bias, int K,
                                                   bf16_t* __restrict__ out_bf,
                                                   const float* resid) {
  __shared__ __align__(16) bf16_t As[2][8192];  // [buf][128*64]
  __shared__ __align__(16) bf16_t Bs[2][8192];
  int tid = threadIdx.x;
  int lane = tid & 63, wv = tid >> 6;
  int wm = wv >> 1, wn = wv & 1;

  int GX = gridDim.x, GY = gridDim.y;
  int flat = blockIdx.x + blockIdx.y * GX;
  int xcd = flat & 7, ii = flat >> 3;
  int iq = ii / GX;
  int by = xcd * (GY >> 3) + iq;
  int bx = ii - iq * GX;
  long m0 = (long)by * 128;
  int n0 = bx * 128;
  int lr = lane & 15, g = lane >> 4;

  int csw = (((lane & 7) ^ (lane >> 3)) << 3);
  const bf16_t* gA = A + (m0 + wv * 32 + (lane >> 3)) * K + csw;
  const bf16_t* gB = Bw + (long)(n0 + wv * 32 + (lane >> 3)) * K + csw;

  f32x4 acc[4][4] = {};

#define STAGE(buf, k0)                                                    \
  do {                                                                    \
    _Pragma("unroll") for (int s = 0; s < 4; ++s) {                       \
      GLDS(gA + (long)s * 8 * K + (k0), As[buf] + wv * 2048 + s * 512);   \
      GLDS(gB + (long)s * 8 * K + (k0), Bs[buf] + wv * 2048 + s * 512);   \
    }                                                                     \
  } while (0)

  int nt = K >> 6;
  STAGE(0, 0);
  for (int t = 0; t < nt; ++t) {
    int tb = t & 1;
    if (t + 1 < nt) {
      STAGE(tb ^ 1, (t + 1) << 6);
      asm volatile("s_waitcnt vmcnt(8)" ::: "memory");
    } else {
      asm volatile("s_waitcnt vmcnt(0)" ::: "memory");
    }
    BAR;
    SCHED0;
#pragma unroll
    for (int kk = 0; kk < 2; ++kk) {
      bf16x8 af[4], bfr[4];
#pragma unroll
      for (int mf = 0; mf < 4; ++mf)
        af[mf] = *(const bf16x8*)(As[tb] + (wm * 64 + mf * 16 + lr) * 64 +
                                  (((kk * 4 + g) ^ (lr & 7)) << 3));
#pragma unroll
      for (int nf = 0; nf < 4; ++nf)
        bfr[nf] = *(const bf16x8*)(Bs[tb] + (wn * 64 + nf * 16 + lr) * 64 +
                                   (((kk * 4 + g) ^ (lr & 7)) << 3));
#pragma unroll
      for (int mf = 0; mf < 4; ++mf)
#pragma unroll
        for (int nf = 0; nf < 4; ++nf)
          acc[mf][nf] = MFMA(af[mf], bfr[nf], acc[mf][nf], 0, 0, 0);
    }
    BAR;
  }
#undef STAGE

#pragma unroll
  for (int mf = 0; mf < 4; ++mf) {
#pragma unroll
    for (int nf = 0; nf < 4; ++nf) {
      long mb = m0 + wm * 64 + mf * 16 + 4 * g;
      int n = n0 + wn * 64 + nf * 16 + lr;
      float bn = bias[n];
      if (EPI == 0) {
        long b_ = mb >> 6;
        int tok = (int)(mb & 63);
        int which = n >> 8, rem = n & 255, head = rem >> 5, d = rem & 31;
        if (which == 2) {
          bf16x4 o;
#pragma unroll
          for (int r = 0; r < 4; ++r) o[r] = (bf16_t)(acc[mf][nf][r] + bn);
          *(bf16x4*)(out_bf + 2 * QKV_SEG + ((b_ * 8 + head) * 32 + d) * 64 + tok) = o;
        } else {
          long base = (long)which * QKV_SEG + ((b_ * 8 + head) * 64 + tok) * 32 + d;
#pragma unroll
          for (int r = 0; r < 4; ++r) out_bf[base + r * 32] = (bf16_t)(acc[mf][nf][r] + bn);
        }
      } else {
#pragma unroll
        for (int r = 0; r < 4; ++r) {
          long m = mb + r;
          long b_ = m >> 6; int tok = (int)(m & 63);
          int bb = (int)(b_ >> 8), win = (int)(b_ & 255);
          int wh = win >> 4, ww = win & 15;
          int jj0 = tok >> 3, jj = tok & 7;
          int hh = (wh * 8 + jj0 + 4) & 127, wp = (ww * 8 + jj + 4) & 127;
          long dst = (((long)bb << 14) + (hh << 7) + wp) * 256 + n;
          out_bf[dst] = (bf16_t)(acc[mf][nf][r] + bn + resid[dst]);
        }
      }
    }
  }
}

// ---------------- fused MLP v5: LN2 + FC1 + GeLU + FC2 + residual ----------------
// 64 tokens/block, EIGHT waves (512 thr), 51KB LDS -> 3 blocks/CU = 24 waves/CU.
// Per-wave state halved vs v4 (FC1: 16 hid rows, acc1=16 VGPR; FC2: 32 n-cols,
// acc2=32 VGPR) -> fits 6 waves/EU (launch_bounds (512,6), VGPR<=85).
// Weight fragments batch-prefetched (proven R12); GeLU is tanh-form (gelu_f).
__global__ __launch_bounds__(512, 6) void mlp_kernel(const bf16_t* __restrict__ x1b,
                                                     float* __restrict__ out,
                                                     const float* __restrict__ gw,
                                                     const float* __restrict__ gb,
                                                     const bf16_t* __restrict__ w1,
                                                     const float* __restrict__ b1,
                                                     const bf16_t* __restrict__ w2,
                                                     const float* __restrict__ b2) {
  __shared__ __align__(16) bf16_t ys[64][264];  // LN output (+8 pad)
  __shared__ __align__(16) bf16_t hs[64][136];  // h chunk [tok][hid128] (+8 pad)
  int tid = threadIdx.x, lane = tid & 63, wv = tid >> 6;  // wv in 0..7
  long m0 = (long)blockIdx.x * 64;
  int lr = lane & 15, lk = (lane >> 4) * 8, g = lane >> 4;

  // ---- LN2 (bf16 in): 8 rows per wave ----
  float4 g4 = *(const float4*)(gw + lane * 4);
  float4 b4 = *(const float4*)(gb + lane * 4);
#pragma unroll
  for (int i = 0; i < 8; ++i) {
    int r = wv * 8 + i;
    bf16x4 xv = *(const bf16x4*)(x1b + (m0 + r) * 256 + lane * 4);
    float v0 = (float)xv[0], v1 = (float)xv[1], v2 = (float)xv[2], v3 = (float)xv[3];
    float s = v0 + v1 + v2 + v3;
    float s2 = v0 * v0 + v1 * v1 + v2 * v2 + v3 * v3;
#pragma unroll
    for (int msk = 1; msk < 64; msk <<= 1) {
      s += __shfl_xor(s, msk);
      s2 += __shfl_xor(s2, msk);
    }
    float mean = s * (1.f / 256.f);
    float var = s2 * (1.f / 256.f) - mean * mean;
    float rs = rsqrtf(var + 1e-5f);
    bf16x4 o;
    o[0] = (bf16_t)((v0 - mean) * rs * g4.x + b4.x);
    o[1] = (bf16_t)((v1 - mean) * rs * g4.y + b4.y);
    o[2] = (bf16_t)((v2 - mean) * rs * g4.z + b4.z);
    o[3] = (bf16_t)((v3 - mean) * rs * g4.w + b4.w);
    *(bf16x4*)(&ys[r][lane * 4]) = o;
  }
  __syncthreads();

  f32x4 acc2[4][2] = {};  // FC2: 64 tok x 32 n per wave (n = wv*32..)

  for (int hc = 0; hc < 8; ++hc) {
    // ---- FC1' chunk: h^T[128 hid][64 tok]; wave owns 16 hid rows ----
    f32x4 acc1[4] = {};  // nt = 0..3 (4 x 16-token groups)
#pragma unroll
    for (int half = 0; half < 2; ++half) {
      bf16x8 xf[4];  // batch-issue 4 independent w1 loads
#pragma unroll
      for (int kb = 0; kb < 4; ++kb)
        xf[kb] = *(const bf16x8*)(w1 + (long)(hc * 128 + wv * 16 + lr) * 256 +
                                  (half * 4 + kb) * 32 + lk);
#pragma unroll
      for (int kb = 0; kb < 4; ++kb) {
        bf16x8 yf[4];
#pragma unroll
        for (int nt = 0; nt < 4; ++nt)
          yf[nt] = *(const bf16x8*)(&ys[nt * 16 + lr][(half * 4 + kb) * 32 + lk]);
#pragma unroll
        for (int nt = 0; nt < 4; ++nt) acc1[nt] = MFMA(xf[kb], yf[nt], acc1[nt], 0, 0, 0);
      }
    }
    // bias + GeLU -> hs[tok][hid] (bf16x4, hidden-consecutive)
    {
      float4 bb = *(const float4*)(b1 + hc * 128 + wv * 16 + 4 * g);
#pragma unroll
      for (int nt = 0; nt < 4; ++nt) {
        bf16x4 o;
#pragma unroll
        for (int r = 0; r < 4; ++r) o[r] = (bf16_t)gelu_f(acc1[nt][r] + ((const float*)&bb)[r]);
        *(bf16x4*)(&hs[nt * 16 + lr][wv * 16 + 4 * g]) = o;
      }
    }
    __syncthreads();
    // ---- FC2 accumulate: out[tok][n] += h[tok][k]*w2[n][k], k = this 128-chunk ----
#pragma unroll
    for (int half = 0; half < 2; ++half) {
      bf16x8 bw[2][2];  // batch-issue 4 independent w2 loads
#pragma unroll
      for (int kb = 0; kb < 2; ++kb)
#pragma unroll
        for (int nf = 0; nf < 2; ++nf)
          bw[kb][nf] = *(const bf16x8*)(w2 + (long)(wv * 32 + nf * 16 + lr) * 1024 + hc * 128 +
                                        (half * 2 + kb) * 32 + lk);
#pragma unroll
      for (int kb = 0; kb < 2; ++kb) {
        bf16x8 ah[4];
#pragma unroll
        for (int mf = 0; mf < 4; ++mf)
          ah[mf] = *(const bf16x8*)(&hs[mf * 16 + lr][(half * 2 + kb) * 32 + lk]);
#pragma unroll
        for (int mf = 0; mf < 4; ++mf)
#pragma unroll
          for (int nf = 0; nf < 2; ++nf)
            acc2[mf][nf] = MFMA(ah[mf], bw[kb][nf], acc2[mf][nf], 0, 0, 0);
      }
    }
    __syncthreads();  // hs reads done before next chunk overwrites
  }

  // ---- epilogue: out = x1 + b2 + mlp (sole writer of d_out) ----
#pragma unroll
  for (int mf = 0; mf < 4; ++mf)
#pragma unroll
    for (int nf = 0; nf < 2; ++nf) {
      int n = wv * 32 + nf * 16 + lr;
      float bn = b2[n];
#pragma unroll
      for (int r = 0; r < 4; ++r) {
        long row = m0 + mf * 16 + 4 * g + r;
        out[row * 256 + n] = acc2[mf][nf][r] + bn + (float)x1b[row * 256 + n];
      }
    }
}

// ---------------- per-window attention: 4 waves x 2 heads ----------------
__global__ __launch_bounds__(256) void attn_kernel(const bf16_t* __restrict__ qkv,
                                                   const float* __restrict__ rpb,
                                                   bf16_t* __restrict__ attn_out) {
  __shared__ float rpb_s[1800];       // 225 x 8
  __shared__ bf16_t P[4][64][72];     // +8 pad
  int tid = threadIdx.x, lane = tid & 63, wv = tid >> 6;
  long b_ = blockIdx.x;
  for (int i = tid; i < 1800; i += 256) rpb_s[i] = rpb[i];
  __syncthreads();
  const bf16_t* q = qkv;
  const bf16_t* k = qkv + QKV_SEG;
  const bf16_t* vt = qkv + 2 * QKV_SEG;
  int lr = lane & 15, lk = (lane >> 4) * 8, g = lane >> 4;
  const float scale = 0.17677669529663688f;  // 32^-0.5

  for (int hh = 0; hh < 2; ++hh) {
    int head = wv * 2 + hh;
    long base = (b_ * 8 + head) * 2048;
    bf16x8 af[4], bfr[4];
#pragma unroll
    for (int mf = 0; mf < 4; ++mf)
      af[mf] = *(const bf16x8*)(q + base + (mf * 16 + lr) * 32 + lk);
#pragma unroll
    for (int nf = 0; nf < 4; ++nf)
      bfr[nf] = *(const bf16x8*)(k + base + (nf * 16 + lr) * 32 + lk);
    f32x4 S[4][4] = {};
#pragma unroll
    for (int mf = 0; mf < 4; ++mf)
#pragma unroll
      for (int nf = 0; nf < 4; ++nf)
        S[mf][nf] = MFMA(af[mf], bfr[nf], S[mf][nf], 0, 0, 0);
#pragma unroll
    for (int mf = 0; mf < 4; ++mf)
#pragma unroll
      for (int nf = 0; nf < 4; ++nf)
#pragma unroll
        for (int r = 0; r < 4; ++r) {
          int i = mf * 16 + 4 * g + r, j = nf * 16 + lr;
          int rel = ((i >> 3) - (j >> 3) + 7) * 15 + ((i & 7) - (j & 7) + 7);
          S[mf][nf][r] = S[mf][nf][r] * scale + rpb_s[rel * 8 + head];
        }
#pragma unroll
    for (int mf = 0; mf < 4; ++mf) {
#pragma unroll
      for (int r = 0; r < 4; ++r) {
        float mx = fmaxf(fmaxf(S[mf][0][r], S[mf][1][r]), fmaxf(S[mf][2][r], S[mf][3][r]));
#pragma unroll
        for (int msk = 1; msk < 16; msk <<= 1) mx = fmaxf(mx, __shfl_xor(mx, msk));
        float sm = 0.f;
#pragma unroll
        for (int nf = 0; nf < 4; ++nf) {
          float e = __expf(S[mf][nf][r] - mx);
          S[mf][nf][r] = e;
          sm += e;
        }
#pragma unroll
        for (int msk = 1; msk < 16; msk <<= 1) sm += __shfl_xor(sm, msk);
        float is = 1.f / sm;
        int i = mf * 16 + 4 * g + r;
#pragma unroll
        for (int nf = 0; nf < 4; ++nf) P[wv][i][nf * 16 + lr] = (bf16_t)(S[mf][nf][r] * is);
      }
    }
    f32x4 O[4][2] = {};
#pragma unroll
    for (int ks = 0; ks < 2; ++ks) {
      int j0 = ks * 32;
      bf16x8 pa[4], vb[2];
#pragma unroll
      for (int mf = 0; mf < 4; ++mf) pa[mf] = *(const bf16x8*)(&P[wv][mf * 16 + lr][j0 + lk]);
#pragma unroll
      for (int nf = 0; nf < 2; ++nf)
        vb[nf] = *(const bf16x8*)(vt + base + (nf * 16 + lr) * 64 + j0 + lk);
#pragma unroll
      for (int mf = 0; mf < 4; ++mf)
#pragma unroll
        for (int nf = 0; nf < 2; ++nf)
          O[mf][nf] = MFMA(pa[mf], vb[nf], O[mf][nf], 0, 0, 0);
    }
#pragma unroll
    for (int mf = 0; mf < 4; ++mf)
#pragma unroll
      for (int nf = 0; nf < 2; ++nf)
#pragma unroll
        for (int r = 0; r < 4; ++r) {
          int i = mf * 16 + 4 * g + r, d = nf * 16 + lr;
          attn_out[(b_ * 64 + i) * 256 + head * 32 + d] = (bf16_t)O[mf][nf][r];
        }
  }
}

extern "C" void kernel_launch(void* const* d_in, const int* in_sizes, int n_in,
                              void* d_out, int out_size, void* d_ws, size_t ws_size,
                              hipStream_t stream) {
  const float* x = (const float*)d_in[0];
  const float* n1w = (const float*)d_in[1];
  const float* n1b = (const float*)d_in[2];
  const float* qkv_w = (const float*)d_in[3];
  const float* qkv_b = (const float*)d_in[4];
  const float* rpb = (const float*)d_in[5];
  const float* proj_w = (const float*)d_in[6];
  const float* proj_b = (const float*)d_in[7];
  const float* n2w = (const float*)d_in[8];
  const float* n2b = (const float*)d_in[9];
  const float* fc1_w = (const float*)d_in[10];
  const float* fc1_b = (const float*)d_in[11];
  const float* fc2_w = (const float*)d_in[12];
  const float* fc2_b = (const float*)d_in[13];
  float* out = (float*)d_out;

  char* ws = (char*)d_ws;
  bf16_t* bufA = (bf16_t*)ws;                       // qkv (201MB)
  bf16_t* x1b = (bf16_t*)(ws + 201326592L);         // x1 bf16 (67MB)
  bf16_t* bufB = (bf16_t*)(ws + 268435456L);        // xw / attn_out (67MB)
  bf16_t* wq = (bf16_t*)(ws + 335544320L);          // bf16 weights (1.6MB)
  bf16_t* wp = wq + 196608;
  bf16_t* w1 = wp + 65536;
  bf16_t* w2 = w1 + 262144;

  // weights -> bf16
  cvt_kernel<<<192, 256, 0, stream>>>(qkv_w, wq);
  cvt_kernel<<<64, 256, 0, stream>>>(proj_w, wp);
  cvt_kernel<<<256, 256, 0, stream>>>(fc1_w, w1);
  cvt_kernel<<<256, 256, 0, stream>>>(fc2_w, w2);

  // LN1 + shift + window partition -> xw (bufB)
  ln_kernel<<<32768, 256, 0, stream>>>(x, n1w, n1b, bufB);
  // QKV GEMM -> q/k/v_t (bufA)
  gemm_kernel<0><<<dim3(6, 1024), 256, 0, stream>>>(bufB, wq, qkv_b, 256, bufA, nullptr);
  // window attention -> attn_out (bufB)
  attn_kernel<<<2048, 256, 0, stream>>>(bufA, rpb, bufB);
  // proj + reverse shift + residual(x) -> x1 bf16
  gemm_kernel<1><<<dim3(2, 1024), 256, 0, stream>>>(bufB, wp, proj_b, 256, x1b, x);
  // fused LN2 + FC1 + GeLU + FC2 + residual -> d_out (fp32, sole writer)
  mlp_kernel<<<2048, 512, 0, stream>>>(x1b, out, n2w, n2b, w1, fc1_b, w2, fc2_b);
}